// Round 9
// baseline (1826.163 us; speedup 1.0000x reference)
//
#include <hip/hip_runtime.h>

// B=128 trajectories, N=20000 vars, M=85400 clauses, K=3 literals/clause.
// Inputs: v(B*N) f32, xl(B*M) f32, xs(B*M) f32, param(6) f32,
//         input_sign(B*M*K) f32, input_idx(B*M*K) i32
// Outputs concat: C(B*M), grad_v(B*N), dxl(B*M), dxs(B*M)  -- all f32

#define NMAX 20000     // sv only: 80KB LDS -> 2 blocks/CU = 32 waves
#define BPB  4         // blocks per batch element -> grid 512 = 2 blocks/CU

typedef int   int4v   __attribute__((ext_vector_type(4)));
typedef float float4v __attribute__((ext_vector_type(4)));

__device__ __forceinline__ void clause_math(
    float a0, float a1, float a2, float xlv, float xsv, float zeta,
    float& C, float& g0, float& g1, float& g2)
{
    // top-2 with jax.lax.top_k tie semantics (first occurrence wins argmax)
    int k0; float m0, m1;
    if (a0 >= a1) {
        if (a0 >= a2) { k0 = 0; m0 = a0; m1 = fmaxf(a1, a2); }
        else          { k0 = 2; m0 = a2; m1 = fmaxf(a0, a1); }
    } else {
        if (a1 >= a2) { k0 = 1; m0 = a1; m1 = fmaxf(a0, a2); }
        else          { k0 = 2; m0 = a2; m1 = fmaxf(a0, a1); }
    }
    C = (1.f - m0) * 0.5f;
    const float T2 = (1.f - m1) * 0.5f;
    const float gl = xlv * xsv;
    const float rC = C * ((1.f + zeta * xlv) * (1.f - xsv));
    g0 = (k0 == 0 ? T2 : C) * gl + (k0 == 0 ? rC : 0.f);
    g1 = (k0 == 1 ? T2 : C) * gl + (k0 == 1 ? rC : 0.f);
    g2 = (k0 == 2 ? T2 : C) * gl + (k0 == 2 ? rC : 0.f);
}

// ---------- fast path: v in LDS (gathers), grad atomics into WORKSPACE ----------
// R3 retried with the atomic target in d_ws (normal cached memory) instead of
// d_out (R3's 1.5GB WRITE_SIZE = every atomic hit HBM = fine-grained alloc
// signature; ws has behaved as normal cached memory all session).
// 80KB LDS -> 2 blocks/CU -> 32 waves; 3 random-LDS ops/clause instead of 6;
// no partial flush + no reduce2 tail.
__global__ __launch_bounds__(1024, 8) void or_priv11(
    const float* __restrict__ v,
    const float* __restrict__ xl,
    const float* __restrict__ xs,
    const float* __restrict__ param,
    const float* __restrict__ sign,
    const int*   __restrict__ idx,
    float* __restrict__ outC,
    float* __restrict__ outdxl,
    float* __restrict__ outdxs,
    float* __restrict__ gws,      // [B][N] in d_ws, pre-zeroed; f32 atomics
    int N, int M, int B, int chunk)
{
    __shared__ float sv[NMAX];   // v slice (gathers stay in LDS -- R1 lesson)

    // XCD swizzle: the BPB=4 blocks of each b land on ONE XCD (grid 512, 64
    // blocks/XCD-chunk; 4b..4b+3 never straddles a chunk) -> v-stage re-reads
    // AND the 80KB atomic target for b stay in that XCD's L2.
    const int id  = blockIdx.x;
    const int cpx = gridDim.x >> 3;
    const int cid = ((gridDim.x & 7) == 0) ? ((id & 7) * cpx + (id >> 3)) : id;
    const int b   = cid >> 2;              // BPB == 4
    const int j   = cid & 3;
    const int tid = threadIdx.x;

    // stage v slice (coalesced float4; later blocks of the quad hit L2)
    {
        const float4v* __restrict__ v4 = (const float4v*)(v + (size_t)b * N);
        float4v* sv4 = (float4v*)sv;
        const int n4 = N >> 2;
        for (int i = tid; i < n4; i += 1024) sv4[i] = v4[i];
        for (int i = (n4 << 2) + tid; i < N; i += 1024)
            sv[i] = v[(size_t)b * N + i];
    }
    __syncthreads();

    const float alpha = param[0], beta = param[1], gamma = param[2];
    const float delta = param[3], eps  = param[4], zeta  = param[5];

    float* __restrict__ ga = gws + (size_t)b * N;   // L2-resident atomic slab

    const int mstart = j * chunk;                 // chunk is a multiple of 4
    const int mend   = min(M, mstart + chunk);
    const int mlen   = mend - mstart;

    if (mlen > 0 && (mlen & 3) == 0) {
        const int ngroups = mlen >> 2;
        // R2's proven load/compute pattern, byte-for-byte
        for (int g = tid; g < ngroups; g += 1024) {
            const size_t base = (size_t)b * M + mstart + ((size_t)g << 2);
            const int4v*   __restrict__ ip = (const int4v*)(idx + base * 3);
            const float4v* __restrict__ sp = (const float4v*)(sign + base * 3);
            const int4v   ia = __builtin_nontemporal_load(ip + 0);
            const int4v   ib = __builtin_nontemporal_load(ip + 1);
            const int4v   ic = __builtin_nontemporal_load(ip + 2);
            const float4v sa = __builtin_nontemporal_load(sp + 0);
            const float4v sb = __builtin_nontemporal_load(sp + 1);
            const float4v sc = __builtin_nontemporal_load(sp + 2);
            const float4v xl4 = __builtin_nontemporal_load((const float4v*)(xl + base));
            const float4v xs4 = __builtin_nontemporal_load((const float4v*)(xs + base));

            const int   ii[12] = {ia.x, ia.y, ia.z, ia.w, ib.x, ib.y, ib.z, ib.w,
                                  ic.x, ic.y, ic.z, ic.w};
            const float ss[12] = {sa.x, sa.y, sa.z, sa.w, sb.x, sb.y, sb.z, sb.w,
                                  sc.x, sc.y, sc.z, sc.w};
            const float xlA[4] = {xl4.x, xl4.y, xl4.z, xl4.w};
            const float xsA[4] = {xs4.x, xs4.y, xs4.z, xs4.w};
            float Cv[4], dxlv[4], dxsv[4];

            #pragma unroll
            for (int c = 0; c < 4; ++c) {
                const int   i0 = ii[3*c], i1 = ii[3*c+1], i2 = ii[3*c+2];
                const float s0 = ss[3*c], s1 = ss[3*c+1], s2 = ss[3*c+2];
                const float a0 = sv[i0] * s0, a1 = sv[i1] * s1, a2 = sv[i2] * s2;
                float C, g0, g1, g2;
                clause_math(a0, a1, a2, xlA[c], xsA[c], zeta, C, g0, g1, g2);
                unsafeAtomicAdd(&ga[i0], -g0 * s0);   // fire-and-forget, L2 (ws)
                unsafeAtomicAdd(&ga[i1], -g1 * s1);
                unsafeAtomicAdd(&ga[i2], -g2 * s2);
                Cv[c]   = C;
                dxlv[c] = -alpha * (C - delta);
                dxsv[c] = -beta * (xsA[c] + eps) * (C - gamma);
            }
            const float4v cv  = {Cv[0], Cv[1], Cv[2], Cv[3]};
            const float4v lv  = {dxlv[0], dxlv[1], dxlv[2], dxlv[3]};
            const float4v svo = {dxsv[0], dxsv[1], dxsv[2], dxsv[3]};
            __builtin_nontemporal_store(cv,  (float4v*)(outC + base));
            __builtin_nontemporal_store(lv,  (float4v*)(outdxl + base));
            __builtin_nontemporal_store(svo, (float4v*)(outdxs + base));
        }
    } else {
        // ragged tail fallback (not hit for M%4==0 shapes)
        for (int m = mstart + tid; m < mend; m += 1024) {
            const size_t bm  = (size_t)b * M + m;
            const size_t bm3 = bm * 3;
            const int   i0 = idx[bm3 + 0], i1 = idx[bm3 + 1], i2 = idx[bm3 + 2];
            const float s0 = sign[bm3 + 0], s1 = sign[bm3 + 1], s2 = sign[bm3 + 2];
            const float a0 = sv[i0] * s0, a1 = sv[i1] * s1, a2 = sv[i2] * s2;
            const float xlv = xl[bm], xsv = xs[bm];
            float C, g0, g1, g2;
            clause_math(a0, a1, a2, xlv, xsv, zeta, C, g0, g1, g2);
            unsafeAtomicAdd(&ga[i0], -g0 * s0);
            unsafeAtomicAdd(&ga[i1], -g1 * s1);
            unsafeAtomicAdd(&ga[i2], -g2 * s2);
            outC[bm]   = C;
            outdxl[bm] = -alpha * (C - delta);
            outdxs[bm] = -beta * (xsv + eps) * (C - gamma);
        }
    }
}

__global__ __launch_bounds__(256) void zero_f4(float4v* __restrict__ p, int n4) {
    int i = blockIdx.x * blockDim.x + threadIdx.x;
    int stride = gridDim.x * blockDim.x;
    const float4v z = {0.f, 0.f, 0.f, 0.f};
    for (; i < n4; i += stride) p[i] = z;
}

__global__ __launch_bounds__(256) void copy_f4(
    const float4v* __restrict__ src, float4v* __restrict__ dst, int n4)
{
    int i = blockIdx.x * 256 + threadIdx.x;
    const int gs = gridDim.x * 256;
    for (; i < n4; i += gs) dst[i] = src[i];
}

// ---------- fallback path (round-1, global atomics into output) ----------
__global__ __launch_bounds__(256) void or_kernel(
    const float* __restrict__ v, const float* __restrict__ xl,
    const float* __restrict__ xs, const float* __restrict__ param,
    const float* __restrict__ sign, const int* __restrict__ idx,
    float* __restrict__ outC, float* __restrict__ gradv,
    float* __restrict__ outdxl, float* __restrict__ outdxs, int N, int M)
{
    const int m = blockIdx.x * blockDim.x + threadIdx.x;
    const int b = blockIdx.y;
    if (m >= M) return;
    const size_t bm = (size_t)b * M + m;
    const size_t bm3 = bm * 3;
    const int   i0 = idx[bm3 + 0], i1 = idx[bm3 + 1], i2 = idx[bm3 + 2];
    const float s0 = sign[bm3 + 0], s1 = sign[bm3 + 1], s2 = sign[bm3 + 2];
    const float* __restrict__ vb = v + (size_t)b * N;
    const float a0 = vb[i0] * s0, a1 = vb[i1] * s1, a2 = vb[i2] * s2;
    const float xlv = xl[bm], xsv = xs[bm];
    const float alpha = param[0], beta = param[1], gamma = param[2];
    const float delta = param[3], eps  = param[4], zeta  = param[5];

    float C, g0, g1, g2;
    clause_math(a0, a1, a2, xlv, xsv, zeta, C, g0, g1, g2);

    float* __restrict__ gb = gradv + (size_t)b * N;
    atomicAdd(&gb[i0], -g0 * s0);
    atomicAdd(&gb[i1], -g1 * s1);
    atomicAdd(&gb[i2], -g2 * s2);

    outC[bm]   = C;
    outdxl[bm] = -alpha * (C - delta);
    outdxs[bm] = -beta * (xsv + eps) * (C - gamma);
}

extern "C" void kernel_launch(void* const* d_in, const int* in_sizes, int n_in,
                              void* d_out, int out_size, void* d_ws, size_t ws_size,
                              hipStream_t stream) {
    const float* v     = (const float*)d_in[0];
    const float* xl    = (const float*)d_in[1];
    const float* xs    = (const float*)d_in[2];
    const float* param = (const float*)d_in[3];
    const float* sign  = (const float*)d_in[4];
    const int*   idx   = (const int*)d_in[5];

    const int B = 128;
    const int N = in_sizes[0] / B;   // 20000
    const int M = in_sizes[1] / B;   // 85400

    float* outC   = (float*)d_out;
    float* gradv  = outC   + (size_t)in_sizes[1];
    float* outdxl = gradv  + (size_t)in_sizes[0];
    float* outdxs = outdxl + (size_t)in_sizes[1];

    const size_t bn = (size_t)B * N;
    const size_t ws_need = bn * sizeof(float);
    const int n4 = (int)(bn / 4);

    if (N <= NMAX && ws_size >= ws_need && (bn % 4) == 0 && (M % 4) == 0) {
        float* gws = (float*)d_ws;
        // zero the ws accumulator, scatter with fire-and-forget f32 atomics
        // (normal cached memory -> resolved in L2), then copy into gradv.
        zero_f4<<<dim3(min(2048, (n4 + 255) / 256)), dim3(256), 0, stream>>>(
            (float4v*)gws, n4);
        const int chunk = (((M + BPB - 1) / BPB) + 3) & ~3;
        or_priv11<<<dim3(BPB * B), dim3(1024), 0, stream>>>(
            v, xl, xs, param, sign, idx, outC, outdxl, outdxs,
            gws, N, M, B, chunk);
        copy_f4<<<dim3(min(2048, (n4 + 255) / 256)), dim3(256), 0, stream>>>(
            (const float4v*)gws, (float4v*)gradv, n4);
    } else {
        zero_f4<<<dim3((n4 + 255) / 256), dim3(256), 0, stream>>>((float4v*)gradv, n4);
        dim3 grid((M + 255) / 256, B);
        or_kernel<<<grid, dim3(256), 0, stream>>>(v, xl, xs, param, sign, idx,
                                                  outC, gradv, outdxl, outdxs, N, M);
    }
}

// Round 10
// 631.909 us; speedup vs baseline: 2.8899x; 2.8899x over previous
//
#include <hip/hip_runtime.h>

// B=128 trajectories, N=20000 vars, M=85400 clauses, K=3 literals/clause.
// Inputs: v(B*N) f32, xl(B*M) f32, xs(B*M) f32, param(6) f32,
//         input_sign(B*M*K) f32, input_idx(B*M*K) i32
// Outputs concat: C(B*M), grad_v(B*N), dxl(B*M), dxs(B*M)  -- all f32
//
// R10 = ABLATION ROUND (guide common-mistake #8): or_ab<1> (sequential LDS
// indices, garbage results) runs first, or_ab<0> (exact R2 winner) runs
// second and overwrites everything. Per-dispatch rocprof timings + total
// discriminate stream-BW wall (T-A) vs LDS-random wall (T-B).

#define NMAX 20000     // sv (80KB) + sg (80KB) = 160KB LDS -> 1 block/CU
#define BPB  2         // clause-chunks per batch element -> grid 256 = 1/CU

typedef int   int4v   __attribute__((ext_vector_type(4)));
typedef float float4v __attribute__((ext_vector_type(4)));

__device__ __forceinline__ void clause_math(
    float a0, float a1, float a2, float xlv, float xsv, float zeta,
    float& C, float& g0, float& g1, float& g2)
{
    // top-2 with jax.lax.top_k tie semantics (first occurrence wins argmax)
    int k0; float m0, m1;
    if (a0 >= a1) {
        if (a0 >= a2) { k0 = 0; m0 = a0; m1 = fmaxf(a1, a2); }
        else          { k0 = 2; m0 = a2; m1 = fmaxf(a0, a1); }
    } else {
        if (a1 >= a2) { k0 = 1; m0 = a1; m1 = fmaxf(a0, a2); }
        else          { k0 = 2; m0 = a2; m1 = fmaxf(a0, a1); }
    }
    C = (1.f - m0) * 0.5f;
    const float T2 = (1.f - m1) * 0.5f;
    const float gl = xlv * xsv;
    const float rC = C * ((1.f + zeta * xlv) * (1.f - xsv));
    g0 = (k0 == 0 ? T2 : C) * gl + (k0 == 0 ? rC : 0.f);
    g1 = (k0 == 1 ? T2 : C) * gl + (k0 == 1 ? rC : 0.f);
    g2 = (k0 == 2 ? T2 : C) * gl + (k0 == 2 ? rC : 0.f);
}

// MODE 0: exact R2 winner (real gather/atomic indices from idx stream).
// MODE 1: NOLDS probe -- identical global loads (kept live via asm sink),
//         identical math/atomics/stores, but LDS indices replaced by
//         conflict-free sequential (tid*17 stride -> 32 banks, 2 lanes/bank).
template<int MODE>
__global__ __launch_bounds__(1024, 4) void or_ab(
    const float* __restrict__ v,
    const float* __restrict__ xl,
    const float* __restrict__ xs,
    const float* __restrict__ param,
    const float* __restrict__ sign,
    const int*   __restrict__ idx,
    float* __restrict__ outC,
    float* __restrict__ outdxl,
    float* __restrict__ outdxs,
    float* __restrict__ partial,   // [BPB][B][N]
    int N, int M, int B, int chunk)
{
    __shared__ float sv[NMAX];   // v slice (gathers stay in LDS -- R1 lesson)
    __shared__ float sg[NMAX];   // grad accumulator (stays in LDS -- R3/R9 lesson)

    // XCD swizzle: the BPB=2 blocks of each b land on one XCD (v-stage L2 reuse)
    const int id  = blockIdx.x;
    const int cpx = gridDim.x >> 3;
    const int cid = ((gridDim.x & 7) == 0) ? ((id & 7) * cpx + (id >> 3)) : id;
    const int b   = cid >> 1;              // BPB == 2
    const int j   = cid & 1;
    const int tid = threadIdx.x;

    // stage v slice (coalesced float4) + zero grad
    {
        const float4v* __restrict__ v4 = (const float4v*)(v + (size_t)b * N);
        float4v* sv4 = (float4v*)sv;
        float4v* sg4 = (float4v*)sg;
        const int n4 = N >> 2;
        const float4v z = {0.f, 0.f, 0.f, 0.f};
        for (int i = tid; i < n4; i += 1024) {
            sv4[i] = v4[i];
            sg4[i] = z;
        }
        for (int i = (n4 << 2) + tid; i < N; i += 1024) {
            sv[i] = v[(size_t)b * N + i];
            sg[i] = 0.f;
        }
    }
    __syncthreads();

    const float alpha = param[0], beta = param[1], gamma = param[2];
    const float delta = param[3], eps  = param[4], zeta  = param[5];

    const int mstart = j * chunk;                 // chunk is a multiple of 4
    const int mend   = min(M, mstart + chunk);
    const int mlen   = mend - mstart;

    if (mlen > 0 && (mlen & 3) == 0) {
        const int ngroups = mlen >> 2;
        for (int g = tid; g < ngroups; g += 1024) {
            const size_t base = (size_t)b * M + mstart + ((size_t)g << 2);
            const int4v*   __restrict__ ip = (const int4v*)(idx + base * 3);
            const float4v* __restrict__ sp = (const float4v*)(sign + base * 3);
            const int4v   ia = __builtin_nontemporal_load(ip + 0);
            const int4v   ib = __builtin_nontemporal_load(ip + 1);
            const int4v   ic = __builtin_nontemporal_load(ip + 2);
            const float4v sa = __builtin_nontemporal_load(sp + 0);
            const float4v sb = __builtin_nontemporal_load(sp + 1);
            const float4v sc = __builtin_nontemporal_load(sp + 2);
            const float4v xl4 = __builtin_nontemporal_load((const float4v*)(xl + base));
            const float4v xs4 = __builtin_nontemporal_load((const float4v*)(xs + base));

            if constexpr (MODE == 1) {
                // keep idx loads alive (rule #17) even though indices overridden
                asm volatile("" :: "v"(ia), "v"(ib), "v"(ic));
            }

            const int   ii[12] = {ia.x, ia.y, ia.z, ia.w, ib.x, ib.y, ib.z, ib.w,
                                  ic.x, ic.y, ic.z, ic.w};
            const float ss[12] = {sa.x, sa.y, sa.z, sa.w, sb.x, sb.y, sb.z, sb.w,
                                  sc.x, sc.y, sc.z, sc.w};
            const float xlA[4] = {xl4.x, xl4.y, xl4.z, xl4.w};
            const float xsA[4] = {xs4.x, xs4.y, xs4.z, xs4.w};
            float Cv[4], dxlv[4], dxsv[4];

            #pragma unroll
            for (int c = 0; c < 4; ++c) {
                int i0, i1, i2;
                if constexpr (MODE == 0) {
                    i0 = ii[3*c]; i1 = ii[3*c+1]; i2 = ii[3*c+2];
                } else {
                    // sequential, conflict-free (stride 17 mod 32 banks)
                    const int t17 = tid * 17;
                    i0 = (t17 + c * 3 + 0) & 16383;
                    i1 = (t17 + c * 3 + 1) & 16383;
                    i2 = (t17 + c * 3 + 2) & 16383;
                }
                const float s0 = ss[3*c], s1 = ss[3*c+1], s2 = ss[3*c+2];
                const float a0 = sv[i0] * s0, a1 = sv[i1] * s1, a2 = sv[i2] * s2;
                float C, g0, g1, g2;
                clause_math(a0, a1, a2, xlA[c], xsA[c], zeta, C, g0, g1, g2);
                unsafeAtomicAdd(&sg[i0], -g0 * s0);
                unsafeAtomicAdd(&sg[i1], -g1 * s1);
                unsafeAtomicAdd(&sg[i2], -g2 * s2);
                Cv[c]   = C;
                dxlv[c] = -alpha * (C - delta);
                dxsv[c] = -beta * (xsA[c] + eps) * (C - gamma);
            }
            const float4v cv  = {Cv[0], Cv[1], Cv[2], Cv[3]};
            const float4v lv  = {dxlv[0], dxlv[1], dxlv[2], dxlv[3]};
            const float4v svo = {dxsv[0], dxsv[1], dxsv[2], dxsv[3]};
            __builtin_nontemporal_store(cv,  (float4v*)(outC + base));
            __builtin_nontemporal_store(lv,  (float4v*)(outdxl + base));
            __builtin_nontemporal_store(svo, (float4v*)(outdxs + base));
        }
    } else {
        // ragged tail fallback (not hit for M%4==0 shapes)
        for (int m = mstart + tid; m < mend; m += 1024) {
            const size_t bm  = (size_t)b * M + m;
            const size_t bm3 = bm * 3;
            const int   i0 = idx[bm3 + 0], i1 = idx[bm3 + 1], i2 = idx[bm3 + 2];
            const float s0 = sign[bm3 + 0], s1 = sign[bm3 + 1], s2 = sign[bm3 + 2];
            const float a0 = sv[i0] * s0, a1 = sv[i1] * s1, a2 = sv[i2] * s2;
            const float xlv = xl[bm], xsv = xs[bm];
            float C, g0, g1, g2;
            clause_math(a0, a1, a2, xlv, xsv, zeta, C, g0, g1, g2);
            unsafeAtomicAdd(&sg[i0], -g0 * s0);
            unsafeAtomicAdd(&sg[i1], -g1 * s1);
            unsafeAtomicAdd(&sg[i2], -g2 * s2);
            outC[bm]   = C;
            outdxl[bm] = -alpha * (C - delta);
            outdxs[bm] = -beta * (xsv + eps) * (C - gamma);
        }
    }

    __syncthreads();

    // flush grad accumulator to the per-(j,b) partial slab (cached stores:
    // reduce2 then hits L2/L3 instead of HBM)
    {
        float* __restrict__ pj = partial + ((size_t)j * B + b) * N;
        const float4v* sg4 = (const float4v*)sg;
        const int n4 = N >> 2;
        for (int i = tid; i < n4; i += 1024)
            ((float4v*)pj)[i] = sg4[i];
        for (int i = (n4 << 2) + tid; i < N; i += 1024) pj[i] = sg[i];
    }
}

__global__ __launch_bounds__(256) void reduce2(
    const float4v* __restrict__ p, float4v* __restrict__ out, int n4, int stride4)
{
    int i = blockIdx.x * 256 + threadIdx.x;
    const int gs = gridDim.x * 256;
    for (; i < n4; i += gs) {
        const float4v a = p[i];
        const float4v b = p[i + stride4];
        out[i] = a + b;
    }
}

// ---------- fallback path (round-1, global atomics) ----------
__global__ __launch_bounds__(256) void zero_f4(float4v* __restrict__ p, int n4) {
    int i = blockIdx.x * blockDim.x + threadIdx.x;
    int stride = gridDim.x * blockDim.x;
    const float4v z = {0.f, 0.f, 0.f, 0.f};
    for (; i < n4; i += stride) p[i] = z;
}

__global__ __launch_bounds__(256) void or_kernel(
    const float* __restrict__ v, const float* __restrict__ xl,
    const float* __restrict__ xs, const float* __restrict__ param,
    const float* __restrict__ sign, const int* __restrict__ idx,
    float* __restrict__ outC, float* __restrict__ gradv,
    float* __restrict__ outdxl, float* __restrict__ outdxs, int N, int M)
{
    const int m = blockIdx.x * blockDim.x + threadIdx.x;
    const int b = blockIdx.y;
    if (m >= M) return;
    const size_t bm = (size_t)b * M + m;
    const size_t bm3 = bm * 3;
    const int   i0 = idx[bm3 + 0], i1 = idx[bm3 + 1], i2 = idx[bm3 + 2];
    const float s0 = sign[bm3 + 0], s1 = sign[bm3 + 1], s2 = sign[bm3 + 2];
    const float* __restrict__ vb = v + (size_t)b * N;
    const float a0 = vb[i0] * s0, a1 = vb[i1] * s1, a2 = vb[i2] * s2;
    const float xlv = xl[bm], xsv = xs[bm];
    const float alpha = param[0], beta = param[1], gamma = param[2];
    const float delta = param[3], eps  = param[4], zeta  = param[5];

    float C, g0, g1, g2;
    clause_math(a0, a1, a2, xlv, xsv, zeta, C, g0, g1, g2);

    float* __restrict__ gb = gradv + (size_t)b * N;
    atomicAdd(&gb[i0], -g0 * s0);
    atomicAdd(&gb[i1], -g1 * s1);
    atomicAdd(&gb[i2], -g2 * s2);

    outC[bm]   = C;
    outdxl[bm] = -alpha * (C - delta);
    outdxs[bm] = -beta * (xsv + eps) * (C - gamma);
}

extern "C" void kernel_launch(void* const* d_in, const int* in_sizes, int n_in,
                              void* d_out, int out_size, void* d_ws, size_t ws_size,
                              hipStream_t stream) {
    const float* v     = (const float*)d_in[0];
    const float* xl    = (const float*)d_in[1];
    const float* xs    = (const float*)d_in[2];
    const float* param = (const float*)d_in[3];
    const float* sign  = (const float*)d_in[4];
    const int*   idx   = (const int*)d_in[5];

    const int B = 128;
    const int N = in_sizes[0] / B;   // 20000
    const int M = in_sizes[1] / B;   // 85400

    float* outC   = (float*)d_out;
    float* gradv  = outC   + (size_t)in_sizes[1];
    float* outdxl = gradv  + (size_t)in_sizes[0];
    float* outdxs = outdxl + (size_t)in_sizes[1];

    const size_t bn = (size_t)B * N;
    const size_t ws_need = (size_t)BPB * bn * sizeof(float);

    if (N <= NMAX && ws_size >= ws_need && (bn % 4) == 0) {
        float* partial = (float*)d_ws;
        const int chunk = (((M + BPB - 1) / BPB) + 3) & ~3;
        dim3 grid(BPB * B);
        // ABLATION probe first (garbage results, measured by rocprof)...
        or_ab<1><<<grid, dim3(1024), 0, stream>>>(
            v, xl, xs, param, sign, idx, outC, outdxl, outdxs,
            (float*)partial, N, M, B, chunk);
        // ...then the real pass overwrites every output byte (correctness).
        or_ab<0><<<grid, dim3(1024), 0, stream>>>(
            v, xl, xs, param, sign, idx, outC, outdxl, outdxs,
            (float*)partial, N, M, B, chunk);
        const int n4 = (int)(bn / 4);
        const int rblocks = min(2048, (n4 + 255) / 256);
        reduce2<<<dim3(rblocks), dim3(256), 0, stream>>>(
            (const float4v*)partial, (float4v*)gradv, n4, n4);
    } else {
        const int n4 = (int)(bn / 4);
        zero_f4<<<dim3((n4 + 255) / 256), dim3(256), 0, stream>>>((float4v*)gradv, n4);
        dim3 grid((M + 255) / 256, B);
        or_kernel<<<grid, dim3(256), 0, stream>>>(v, xl, xs, param, sign, idx,
                                                  outC, gradv, outdxl, outdxs, N, M);
    }
}

// Round 11
// 463.162 us; speedup vs baseline: 3.9428x; 1.3643x over previous
//
#include <hip/hip_runtime.h>

// B=128 trajectories, N=20000 vars, M=85400 clauses, K=3 literals/clause.
// Inputs: v(B*N) f32, xl(B*M) f32, xs(B*M) f32, param(6) f32,
//         input_sign(B*M*K) f32, input_idx(B*M*K) i32
// Outputs concat: C(B*M), grad_v(B*N), dxl(B*M), dxs(B*M)  -- all f32
//
// R11: R10-MODE0 body (best measured: 186.5us) with ONE change: output
// stores are plain CACHED stores instead of nontemporal. Theory: kernel is
// HBM-service-rate bound (~1.9 TB/s mixed); nt stores write-through and
// compete with reads at fine granularity; cached stores batch in L2.

#define NMAX 20000     // sv (80KB) + sg (80KB) = 160KB LDS -> 1 block/CU
#define BPB  2         // clause-chunks per batch element -> grid 256 = 1/CU

typedef int   int4v   __attribute__((ext_vector_type(4)));
typedef float float4v __attribute__((ext_vector_type(4)));

__device__ __forceinline__ void clause_math(
    float a0, float a1, float a2, float xlv, float xsv, float zeta,
    float& C, float& g0, float& g1, float& g2)
{
    // top-2 with jax.lax.top_k tie semantics (first occurrence wins argmax)
    int k0; float m0, m1;
    if (a0 >= a1) {
        if (a0 >= a2) { k0 = 0; m0 = a0; m1 = fmaxf(a1, a2); }
        else          { k0 = 2; m0 = a2; m1 = fmaxf(a0, a1); }
    } else {
        if (a1 >= a2) { k0 = 1; m0 = a1; m1 = fmaxf(a0, a2); }
        else          { k0 = 2; m0 = a2; m1 = fmaxf(a0, a1); }
    }
    C = (1.f - m0) * 0.5f;
    const float T2 = (1.f - m1) * 0.5f;
    const float gl = xlv * xsv;
    const float rC = C * ((1.f + zeta * xlv) * (1.f - xsv));
    g0 = (k0 == 0 ? T2 : C) * gl + (k0 == 0 ? rC : 0.f);
    g1 = (k0 == 1 ? T2 : C) * gl + (k0 == 1 ? rC : 0.f);
    g2 = (k0 == 2 ? T2 : C) * gl + (k0 == 2 ? rC : 0.f);
}

// ---------- fast path: v + grad in LDS, cached output stores ----------
__global__ __launch_bounds__(1024, 4) void or_priv12(
    const float* __restrict__ v,
    const float* __restrict__ xl,
    const float* __restrict__ xs,
    const float* __restrict__ param,
    const float* __restrict__ sign,
    const int*   __restrict__ idx,
    float* __restrict__ outC,
    float* __restrict__ outdxl,
    float* __restrict__ outdxs,
    float* __restrict__ partial,   // [BPB][B][N]
    int N, int M, int B, int chunk)
{
    __shared__ float sv[NMAX];   // v slice (gathers stay in LDS -- R1 lesson)
    __shared__ float sg[NMAX];   // grad accumulator (stays in LDS -- R3/R9 lesson)

    // XCD swizzle: the BPB=2 blocks of each b land on one XCD (v-stage L2 reuse)
    const int id  = blockIdx.x;
    const int cpx = gridDim.x >> 3;
    const int cid = ((gridDim.x & 7) == 0) ? ((id & 7) * cpx + (id >> 3)) : id;
    const int b   = cid >> 1;              // BPB == 2
    const int j   = cid & 1;
    const int tid = threadIdx.x;

    // stage v slice (coalesced float4) + zero grad
    {
        const float4v* __restrict__ v4 = (const float4v*)(v + (size_t)b * N);
        float4v* sv4 = (float4v*)sv;
        float4v* sg4 = (float4v*)sg;
        const int n4 = N >> 2;
        const float4v z = {0.f, 0.f, 0.f, 0.f};
        for (int i = tid; i < n4; i += 1024) {
            sv4[i] = v4[i];
            sg4[i] = z;
        }
        for (int i = (n4 << 2) + tid; i < N; i += 1024) {
            sv[i] = v[(size_t)b * N + i];
            sg[i] = 0.f;
        }
    }
    __syncthreads();

    const float alpha = param[0], beta = param[1], gamma = param[2];
    const float delta = param[3], eps  = param[4], zeta  = param[5];

    const int mstart = j * chunk;                 // chunk is a multiple of 4
    const int mend   = min(M, mstart + chunk);
    const int mlen   = mend - mstart;

    if (mlen > 0 && (mlen & 3) == 0) {
        const int ngroups = mlen >> 2;
        for (int g = tid; g < ngroups; g += 1024) {
            const size_t base = (size_t)b * M + mstart + ((size_t)g << 2);
            const int4v*   __restrict__ ip = (const int4v*)(idx + base * 3);
            const float4v* __restrict__ sp = (const float4v*)(sign + base * 3);
            const int4v   ia = __builtin_nontemporal_load(ip + 0);
            const int4v   ib = __builtin_nontemporal_load(ip + 1);
            const int4v   ic = __builtin_nontemporal_load(ip + 2);
            const float4v sa = __builtin_nontemporal_load(sp + 0);
            const float4v sb = __builtin_nontemporal_load(sp + 1);
            const float4v sc = __builtin_nontemporal_load(sp + 2);
            const float4v xl4 = __builtin_nontemporal_load((const float4v*)(xl + base));
            const float4v xs4 = __builtin_nontemporal_load((const float4v*)(xs + base));

            const int   ii[12] = {ia.x, ia.y, ia.z, ia.w, ib.x, ib.y, ib.z, ib.w,
                                  ic.x, ic.y, ic.z, ic.w};
            const float ss[12] = {sa.x, sa.y, sa.z, sa.w, sb.x, sb.y, sb.z, sb.w,
                                  sc.x, sc.y, sc.z, sc.w};
            const float xlA[4] = {xl4.x, xl4.y, xl4.z, xl4.w};
            const float xsA[4] = {xs4.x, xs4.y, xs4.z, xs4.w};
            float Cv[4], dxlv[4], dxsv[4];

            #pragma unroll
            for (int c = 0; c < 4; ++c) {
                const int   i0 = ii[3*c], i1 = ii[3*c+1], i2 = ii[3*c+2];
                const float s0 = ss[3*c], s1 = ss[3*c+1], s2 = ss[3*c+2];
                const float a0 = sv[i0] * s0, a1 = sv[i1] * s1, a2 = sv[i2] * s2;
                float C, g0, g1, g2;
                clause_math(a0, a1, a2, xlA[c], xsA[c], zeta, C, g0, g1, g2);
                unsafeAtomicAdd(&sg[i0], -g0 * s0);
                unsafeAtomicAdd(&sg[i1], -g1 * s1);
                unsafeAtomicAdd(&sg[i2], -g2 * s2);
                Cv[c]   = C;
                dxlv[c] = -alpha * (C - delta);
                dxsv[c] = -beta * (xsA[c] + eps) * (C - gamma);
            }
            const float4v cv  = {Cv[0], Cv[1], Cv[2], Cv[3]};
            const float4v lv  = {dxlv[0], dxlv[1], dxlv[2], dxlv[3]};
            const float4v svo = {dxsv[0], dxsv[1], dxsv[2], dxsv[3]};
            // CACHED stores (the R11 change): absorb into L2, write back in
            // batches -> HBM write service decoupled from wave progress.
            *(float4v*)(outC   + base) = cv;
            *(float4v*)(outdxl + base) = lv;
            *(float4v*)(outdxs + base) = svo;
        }
    } else {
        // ragged tail fallback (not hit for M%4==0 shapes)
        for (int m = mstart + tid; m < mend; m += 1024) {
            const size_t bm  = (size_t)b * M + m;
            const size_t bm3 = bm * 3;
            const int   i0 = idx[bm3 + 0], i1 = idx[bm3 + 1], i2 = idx[bm3 + 2];
            const float s0 = sign[bm3 + 0], s1 = sign[bm3 + 1], s2 = sign[bm3 + 2];
            const float a0 = sv[i0] * s0, a1 = sv[i1] * s1, a2 = sv[i2] * s2;
            const float xlv = xl[bm], xsv = xs[bm];
            float C, g0, g1, g2;
            clause_math(a0, a1, a2, xlv, xsv, zeta, C, g0, g1, g2);
            unsafeAtomicAdd(&sg[i0], -g0 * s0);
            unsafeAtomicAdd(&sg[i1], -g1 * s1);
            unsafeAtomicAdd(&sg[i2], -g2 * s2);
            outC[bm]   = C;
            outdxl[bm] = -alpha * (C - delta);
            outdxs[bm] = -beta * (xsv + eps) * (C - gamma);
        }
    }

    __syncthreads();

    // flush grad accumulator to the per-(j,b) partial slab (cached stores:
    // reduce2 then hits L2/L3 instead of HBM)
    {
        float* __restrict__ pj = partial + ((size_t)j * B + b) * N;
        const float4v* sg4 = (const float4v*)sg;
        const int n4 = N >> 2;
        for (int i = tid; i < n4; i += 1024)
            ((float4v*)pj)[i] = sg4[i];
        for (int i = (n4 << 2) + tid; i < N; i += 1024) pj[i] = sg[i];
    }
}

__global__ __launch_bounds__(256) void reduce2(
    const float4v* __restrict__ p, float4v* __restrict__ out, int n4, int stride4)
{
    int i = blockIdx.x * 256 + threadIdx.x;
    const int gs = gridDim.x * 256;
    for (; i < n4; i += gs) {
        const float4v a = p[i];
        const float4v b = p[i + stride4];
        out[i] = a + b;
    }
}

// ---------- fallback path (round-1, global atomics) ----------
__global__ __launch_bounds__(256) void zero_f4(float4v* __restrict__ p, int n4) {
    int i = blockIdx.x * blockDim.x + threadIdx.x;
    int stride = gridDim.x * blockDim.x;
    const float4v z = {0.f, 0.f, 0.f, 0.f};
    for (; i < n4; i += stride) p[i] = z;
}

__global__ __launch_bounds__(256) void or_kernel(
    const float* __restrict__ v, const float* __restrict__ xl,
    const float* __restrict__ xs, const float* __restrict__ param,
    const float* __restrict__ sign, const int* __restrict__ idx,
    float* __restrict__ outC, float* __restrict__ gradv,
    float* __restrict__ outdxl, float* __restrict__ outdxs, int N, int M)
{
    const int m = blockIdx.x * blockDim.x + threadIdx.x;
    const int b = blockIdx.y;
    if (m >= M) return;
    const size_t bm = (size_t)b * M + m;
    const size_t bm3 = bm * 3;
    const int   i0 = idx[bm3 + 0], i1 = idx[bm3 + 1], i2 = idx[bm3 + 2];
    const float s0 = sign[bm3 + 0], s1 = sign[bm3 + 1], s2 = sign[bm3 + 2];
    const float* __restrict__ vb = v + (size_t)b * N;
    const float a0 = vb[i0] * s0, a1 = vb[i1] * s1, a2 = vb[i2] * s2;
    const float xlv = xl[bm], xsv = xs[bm];
    const float alpha = param[0], beta = param[1], gamma = param[2];
    const float delta = param[3], eps  = param[4], zeta  = param[5];

    float C, g0, g1, g2;
    clause_math(a0, a1, a2, xlv, xsv, zeta, C, g0, g1, g2);

    float* __restrict__ gb = gradv + (size_t)b * N;
    atomicAdd(&gb[i0], -g0 * s0);
    atomicAdd(&gb[i1], -g1 * s1);
    atomicAdd(&gb[i2], -g2 * s2);

    outC[bm]   = C;
    outdxl[bm] = -alpha * (C - delta);
    outdxs[bm] = -beta * (xsv + eps) * (C - gamma);
}

extern "C" void kernel_launch(void* const* d_in, const int* in_sizes, int n_in,
                              void* d_out, int out_size, void* d_ws, size_t ws_size,
                              hipStream_t stream) {
    const float* v     = (const float*)d_in[0];
    const float* xl    = (const float*)d_in[1];
    const float* xs    = (const float*)d_in[2];
    const float* param = (const float*)d_in[3];
    const float* sign  = (const float*)d_in[4];
    const int*   idx   = (const int*)d_in[5];

    const int B = 128;
    const int N = in_sizes[0] / B;   // 20000
    const int M = in_sizes[1] / B;   // 85400

    float* outC   = (float*)d_out;
    float* gradv  = outC   + (size_t)in_sizes[1];
    float* outdxl = gradv  + (size_t)in_sizes[0];
    float* outdxs = outdxl + (size_t)in_sizes[1];

    const size_t bn = (size_t)B * N;
    const size_t ws_need = (size_t)BPB * bn * sizeof(float);

    if (N <= NMAX && ws_size >= ws_need && (bn % 4) == 0) {
        float* partial = (float*)d_ws;
        const int chunk = (((M + BPB - 1) / BPB) + 3) & ~3;
        or_priv12<<<dim3(BPB * B), dim3(1024), 0, stream>>>(
            v, xl, xs, param, sign, idx, outC, outdxl, outdxs,
            (float*)partial, N, M, B, chunk);
        const int n4 = (int)(bn / 4);
        const int rblocks = min(2048, (n4 + 255) / 256);
        reduce2<<<dim3(rblocks), dim3(256), 0, stream>>>(
            (const float4v*)partial, (float4v*)gradv, n4, n4);
    } else {
        const int n4 = (int)(bn / 4);
        zero_f4<<<dim3((n4 + 255) / 256), dim3(256), 0, stream>>>((float4v*)gradv, n4);
        dim3 grid((M + 255) / 256, B);
        or_kernel<<<grid, dim3(256), 0, stream>>>(v, xl, xs, param, sign, idx,
                                                  outC, gradv, outdxl, outdxs, N, M);
    }
}

// Round 12
// 441.054 us; speedup vs baseline: 4.1405x; 1.0501x over previous
//
#include <hip/hip_runtime.h>

// B=128 trajectories, N=20000 vars, M=85400 clauses, K=3 literals/clause.
// Inputs: v(B*N) f32, xl(B*M) f32, xs(B*M) f32, param(6) f32,
//         input_sign(B*M*K) f32, input_idx(B*M*K) i32
// Outputs concat: C(B*M), grad_v(B*N), dxl(B*M), dxs(B*M)  -- all f32
//
// R12: R11 body with ONE change: stream loads are plain CACHED loads
// instead of nontemporal. Theory: nt = no-allocate; the 48B-stride pattern
// touches each 64B line 3x (ip+0/1/2) -> with no L1 allocation each touch
// outside the MSHR window re-fetches from L2 (3x latency-slots + traffic).

#define NMAX 20000     // sv (80KB) + sg (80KB) = 160KB LDS -> 1 block/CU
#define BPB  2         // clause-chunks per batch element -> grid 256 = 1/CU

typedef int   int4v   __attribute__((ext_vector_type(4)));
typedef float float4v __attribute__((ext_vector_type(4)));

__device__ __forceinline__ void clause_math(
    float a0, float a1, float a2, float xlv, float xsv, float zeta,
    float& C, float& g0, float& g1, float& g2)
{
    // top-2 with jax.lax.top_k tie semantics (first occurrence wins argmax)
    int k0; float m0, m1;
    if (a0 >= a1) {
        if (a0 >= a2) { k0 = 0; m0 = a0; m1 = fmaxf(a1, a2); }
        else          { k0 = 2; m0 = a2; m1 = fmaxf(a0, a1); }
    } else {
        if (a1 >= a2) { k0 = 1; m0 = a1; m1 = fmaxf(a0, a2); }
        else          { k0 = 2; m0 = a2; m1 = fmaxf(a0, a1); }
    }
    C = (1.f - m0) * 0.5f;
    const float T2 = (1.f - m1) * 0.5f;
    const float gl = xlv * xsv;
    const float rC = C * ((1.f + zeta * xlv) * (1.f - xsv));
    g0 = (k0 == 0 ? T2 : C) * gl + (k0 == 0 ? rC : 0.f);
    g1 = (k0 == 1 ? T2 : C) * gl + (k0 == 1 ? rC : 0.f);
    g2 = (k0 == 2 ? T2 : C) * gl + (k0 == 2 ? rC : 0.f);
}

// ---------- fast path: v + grad in LDS, cached loads AND stores ----------
__global__ __launch_bounds__(1024, 4) void or_priv13(
    const float* __restrict__ v,
    const float* __restrict__ xl,
    const float* __restrict__ xs,
    const float* __restrict__ param,
    const float* __restrict__ sign,
    const int*   __restrict__ idx,
    float* __restrict__ outC,
    float* __restrict__ outdxl,
    float* __restrict__ outdxs,
    float* __restrict__ partial,   // [BPB][B][N]
    int N, int M, int B, int chunk)
{
    __shared__ float sv[NMAX];   // v slice (gathers stay in LDS -- R1 lesson)
    __shared__ float sg[NMAX];   // grad accumulator (stays in LDS -- R3/R9 lesson)

    // XCD swizzle: the BPB=2 blocks of each b land on one XCD (v-stage L2 reuse)
    const int id  = blockIdx.x;
    const int cpx = gridDim.x >> 3;
    const int cid = ((gridDim.x & 7) == 0) ? ((id & 7) * cpx + (id >> 3)) : id;
    const int b   = cid >> 1;              // BPB == 2
    const int j   = cid & 1;
    const int tid = threadIdx.x;

    // stage v slice (coalesced float4) + zero grad
    {
        const float4v* __restrict__ v4 = (const float4v*)(v + (size_t)b * N);
        float4v* sv4 = (float4v*)sv;
        float4v* sg4 = (float4v*)sg;
        const int n4 = N >> 2;
        const float4v z = {0.f, 0.f, 0.f, 0.f};
        for (int i = tid; i < n4; i += 1024) {
            sv4[i] = v4[i];
            sg4[i] = z;
        }
        for (int i = (n4 << 2) + tid; i < N; i += 1024) {
            sv[i] = v[(size_t)b * N + i];
            sg[i] = 0.f;
        }
    }
    __syncthreads();

    const float alpha = param[0], beta = param[1], gamma = param[2];
    const float delta = param[3], eps  = param[4], zeta  = param[5];

    const int mstart = j * chunk;                 // chunk is a multiple of 4
    const int mend   = min(M, mstart + chunk);
    const int mlen   = mend - mstart;

    if (mlen > 0 && (mlen & 3) == 0) {
        const int ngroups = mlen >> 2;
        for (int g = tid; g < ngroups; g += 1024) {
            const size_t base = (size_t)b * M + mstart + ((size_t)g << 2);
            const int4v*   __restrict__ ip = (const int4v*)(idx + base * 3);
            const float4v* __restrict__ sp = (const float4v*)(sign + base * 3);
            // CACHED loads (the R12 change): L1 allocates -> the 3x line
            // re-touches of the 48B-stride pattern hit L1 instead of L2.
            const int4v   ia = ip[0];
            const int4v   ib = ip[1];
            const int4v   ic = ip[2];
            const float4v sa = sp[0];
            const float4v sb = sp[1];
            const float4v sc = sp[2];
            const float4v xl4 = *(const float4v*)(xl + base);
            const float4v xs4 = *(const float4v*)(xs + base);

            const int   ii[12] = {ia.x, ia.y, ia.z, ia.w, ib.x, ib.y, ib.z, ib.w,
                                  ic.x, ic.y, ic.z, ic.w};
            const float ss[12] = {sa.x, sa.y, sa.z, sa.w, sb.x, sb.y, sb.z, sb.w,
                                  sc.x, sc.y, sc.z, sc.w};
            const float xlA[4] = {xl4.x, xl4.y, xl4.z, xl4.w};
            const float xsA[4] = {xs4.x, xs4.y, xs4.z, xs4.w};
            float Cv[4], dxlv[4], dxsv[4];

            #pragma unroll
            for (int c = 0; c < 4; ++c) {
                const int   i0 = ii[3*c], i1 = ii[3*c+1], i2 = ii[3*c+2];
                const float s0 = ss[3*c], s1 = ss[3*c+1], s2 = ss[3*c+2];
                const float a0 = sv[i0] * s0, a1 = sv[i1] * s1, a2 = sv[i2] * s2;
                float C, g0, g1, g2;
                clause_math(a0, a1, a2, xlA[c], xsA[c], zeta, C, g0, g1, g2);
                unsafeAtomicAdd(&sg[i0], -g0 * s0);
                unsafeAtomicAdd(&sg[i1], -g1 * s1);
                unsafeAtomicAdd(&sg[i2], -g2 * s2);
                Cv[c]   = C;
                dxlv[c] = -alpha * (C - delta);
                dxsv[c] = -beta * (xsA[c] + eps) * (C - gamma);
            }
            const float4v cv  = {Cv[0], Cv[1], Cv[2], Cv[3]};
            const float4v lv  = {dxlv[0], dxlv[1], dxlv[2], dxlv[3]};
            const float4v svo = {dxsv[0], dxsv[1], dxsv[2], dxsv[3]};
            *(float4v*)(outC   + base) = cv;
            *(float4v*)(outdxl + base) = lv;
            *(float4v*)(outdxs + base) = svo;
        }
    } else {
        // ragged tail fallback (not hit for M%4==0 shapes)
        for (int m = mstart + tid; m < mend; m += 1024) {
            const size_t bm  = (size_t)b * M + m;
            const size_t bm3 = bm * 3;
            const int   i0 = idx[bm3 + 0], i1 = idx[bm3 + 1], i2 = idx[bm3 + 2];
            const float s0 = sign[bm3 + 0], s1 = sign[bm3 + 1], s2 = sign[bm3 + 2];
            const float a0 = sv[i0] * s0, a1 = sv[i1] * s1, a2 = sv[i2] * s2;
            const float xlv = xl[bm], xsv = xs[bm];
            float C, g0, g1, g2;
            clause_math(a0, a1, a2, xlv, xsv, zeta, C, g0, g1, g2);
            unsafeAtomicAdd(&sg[i0], -g0 * s0);
            unsafeAtomicAdd(&sg[i1], -g1 * s1);
            unsafeAtomicAdd(&sg[i2], -g2 * s2);
            outC[bm]   = C;
            outdxl[bm] = -alpha * (C - delta);
            outdxs[bm] = -beta * (xsv + eps) * (C - gamma);
        }
    }

    __syncthreads();

    // flush grad accumulator to the per-(j,b) partial slab (cached stores:
    // reduce2 then hits L2/L3 instead of HBM)
    {
        float* __restrict__ pj = partial + ((size_t)j * B + b) * N;
        const float4v* sg4 = (const float4v*)sg;
        const int n4 = N >> 2;
        for (int i = tid; i < n4; i += 1024)
            ((float4v*)pj)[i] = sg4[i];
        for (int i = (n4 << 2) + tid; i < N; i += 1024) pj[i] = sg[i];
    }
}

__global__ __launch_bounds__(256) void reduce2(
    const float4v* __restrict__ p, float4v* __restrict__ out, int n4, int stride4)
{
    int i = blockIdx.x * 256 + threadIdx.x;
    const int gs = gridDim.x * 256;
    for (; i < n4; i += gs) {
        const float4v a = p[i];
        const float4v b = p[i + stride4];
        out[i] = a + b;
    }
}

// ---------- fallback path (round-1, global atomics) ----------
__global__ __launch_bounds__(256) void zero_f4(float4v* __restrict__ p, int n4) {
    int i = blockIdx.x * blockDim.x + threadIdx.x;
    int stride = gridDim.x * blockDim.x;
    const float4v z = {0.f, 0.f, 0.f, 0.f};
    for (; i < n4; i += stride) p[i] = z;
}

__global__ __launch_bounds__(256) void or_kernel(
    const float* __restrict__ v, const float* __restrict__ xl,
    const float* __restrict__ xs, const float* __restrict__ param,
    const float* __restrict__ sign, const int* __restrict__ idx,
    float* __restrict__ outC, float* __restrict__ gradv,
    float* __restrict__ outdxl, float* __restrict__ outdxs, int N, int M)
{
    const int m = blockIdx.x * blockDim.x + threadIdx.x;
    const int b = blockIdx.y;
    if (m >= M) return;
    const size_t bm = (size_t)b * M + m;
    const size_t bm3 = bm * 3;
    const int   i0 = idx[bm3 + 0], i1 = idx[bm3 + 1], i2 = idx[bm3 + 2];
    const float s0 = sign[bm3 + 0], s1 = sign[bm3 + 1], s2 = sign[bm3 + 2];
    const float* __restrict__ vb = v + (size_t)b * N;
    const float a0 = vb[i0] * s0, a1 = vb[i1] * s1, a2 = vb[i2] * s2;
    const float xlv = xl[bm], xsv = xs[bm];
    const float alpha = param[0], beta = param[1], gamma = param[2];
    const float delta = param[3], eps  = param[4], zeta  = param[5];

    float C, g0, g1, g2;
    clause_math(a0, a1, a2, xlv, xsv, zeta, C, g0, g1, g2);

    float* __restrict__ gb = gradv + (size_t)b * N;
    atomicAdd(&gb[i0], -g0 * s0);
    atomicAdd(&gb[i1], -g1 * s1);
    atomicAdd(&gb[i2], -g2 * s2);

    outC[bm]   = C;
    outdxl[bm] = -alpha * (C - delta);
    outdxs[bm] = -beta * (xsv + eps) * (C - gamma);
}

extern "C" void kernel_launch(void* const* d_in, const int* in_sizes, int n_in,
                              void* d_out, int out_size, void* d_ws, size_t ws_size,
                              hipStream_t stream) {
    const float* v     = (const float*)d_in[0];
    const float* xl    = (const float*)d_in[1];
    const float* xs    = (const float*)d_in[2];
    const float* param = (const float*)d_in[3];
    const float* sign  = (const float*)d_in[4];
    const int*   idx   = (const int*)d_in[5];

    const int B = 128;
    const int N = in_sizes[0] / B;   // 20000
    const int M = in_sizes[1] / B;   // 85400

    float* outC   = (float*)d_out;
    float* gradv  = outC   + (size_t)in_sizes[1];
    float* outdxl = gradv  + (size_t)in_sizes[0];
    float* outdxs = outdxl + (size_t)in_sizes[1];

    const size_t bn = (size_t)B * N;
    const size_t ws_need = (size_t)BPB * bn * sizeof(float);

    if (N <= NMAX && ws_size >= ws_need && (bn % 4) == 0) {
        float* partial = (float*)d_ws;
        const int chunk = (((M + BPB - 1) / BPB) + 3) & ~3;
        or_priv13<<<dim3(BPB * B), dim3(1024), 0, stream>>>(
            v, xl, xs, param, sign, idx, outC, outdxl, outdxs,
            (float*)partial, N, M, B, chunk);
        const int n4 = (int)(bn / 4);
        const int rblocks = min(2048, (n4 + 255) / 256);
        reduce2<<<dim3(rblocks), dim3(256), 0, stream>>>(
            (const float4v*)partial, (float4v*)gradv, n4, n4);
    } else {
        const int n4 = (int)(bn / 4);
        zero_f4<<<dim3((n4 + 255) / 256), dim3(256), 0, stream>>>((float4v*)gradv, n4);
        dim3 grid((M + 255) / 256, B);
        or_kernel<<<grid, dim3(256), 0, stream>>>(v, xl, xs, param, sign, idx,
                                                  outC, gradv, outdxl, outdxs, N, M);
    }
}